// Round 5
// baseline (669.667 us; speedup 1.0000x reference)
//
#include <hip/hip_runtime.h>

#define NPTS 1048576
#define NB 32
#define NBINS (NB * NB * NB)   // 32768

#define D0c 32
#define D1c 64
#define D2c 128
#define D3c 256
#define VOX0 (D0c * D0c * D0c)     // 32768
#define VOX1 (D1c * D1c * D1c)     // 262144
#define VOX2 (D2c * D2c * D2c)     // 2097152
#define VOX3 (D3c * D3c * D3c)     // 16777216

typedef float v4f __attribute__((ext_vector_type(4)));
typedef unsigned uv4 __attribute__((ext_vector_type(4)));

__device__ __forceinline__ void nt_store4f(const float4& f, float4* p) {
    __builtin_nontemporal_store(*(const v4f*)&f, (v4f*)p);
}
__device__ __forceinline__ void nt_store4u(const uint4& u, uint4* p) {
    __builtin_nontemporal_store(*(const uv4*)&u, (uv4*)p);
}

// 16B load that only assumes 8B alignment (pair of bf16x4 voxels)
__device__ __forceinline__ uint4 load16(const void* p) {
    uint4 r;
    __builtin_memcpy(&r, p, sizeof(uint4));
    return r;
}

// ---------------- bf16 helpers (RNE) ----------------

__device__ __forceinline__ unsigned bf1(float a) {
    unsigned u = __float_as_uint(a);
    return (u + 0x7FFFu + ((u >> 16) & 1u)) >> 16;
}
__device__ __forceinline__ unsigned bfpack(float lo, float hi) {
    return bf1(lo) | (bf1(hi) << 16);
}
__device__ __forceinline__ float bflo(unsigned u) { return __uint_as_float(u << 16); }
__device__ __forceinline__ float bfhi(unsigned u) { return __uint_as_float(u & 0xFFFF0000u); }

// ---------------- math helpers ----------------

__device__ __forceinline__ float4 lerp4(const float4 a, const float4 b, const float t) {
    return make_float4(a.x + (b.x - a.x) * t,
                       a.y + (b.y - a.y) * t,
                       a.z + (b.z - a.z) * t,
                       a.w + (b.w - a.w) * t);
}

struct CoordW { float tx, ty, tz; int b00, b01, b10, b11, x0, x1; };

template<int D>
__device__ __forceinline__ CoordW mkcoord(float gx, float gy, float gz) {
    CoordW c;
    float x = fminf(fmaxf((gx + 1.0f) * (0.5f * (float)(D - 1)), 0.0f), (float)(D - 1));
    float y = fminf(fmaxf((gy + 1.0f) * (0.5f * (float)(D - 1)), 0.0f), (float)(D - 1));
    float z = fminf(fmaxf((gz + 1.0f) * (0.5f * (float)(D - 1)), 0.0f), (float)(D - 1));
    float xf = floorf(x), yf = floorf(y), zf = floorf(z);
    float tx = x - xf, ty = y - yf, tz = z - zf;
    c.tx = tx * tx * (3.0f - 2.0f * tx);
    c.ty = ty * ty * (3.0f - 2.0f * ty);
    c.tz = tz * tz * (3.0f - 2.0f * tz);
    int x0 = (int)xf, y0 = (int)yf, z0 = (int)zf;
    int y1 = min(y0 + 1, D - 1), z1 = min(z0 + 1, D - 1);
    c.x0 = x0;
    c.x1 = min(x0 + 1, D - 1);
    c.b00 = (z0 * D + y0) * D;
    c.b01 = (z0 * D + y1) * D;
    c.b10 = (z1 * D + y0) * D;
    c.b11 = (z1 * D + y1) * D;
    return c;
}

// row pair: q = {vox xm ch01, vox xm ch23, vox xm+1 ch01, vox xm+1 ch23}
__device__ __forceinline__ float4 rowlerp(const uint4 q, const bool edge, const float tx) {
    float b0 = bflo(q.z), b1 = bfhi(q.z), b2 = bflo(q.w), b3 = bfhi(q.w);
    float a0 = edge ? b0 : bflo(q.x);
    float a1 = edge ? b1 : bfhi(q.x);
    float a2 = edge ? b2 : bflo(q.y);
    float a3 = edge ? b3 : bfhi(q.y);
    return make_float4(a0 + (b0 - a0) * tx, a1 + (b1 - a1) * tx,
                       a2 + (b2 - a2) * tx, a3 + (b3 - a3) * tx);
}

__device__ __forceinline__ float4 reduce_bf(const uint4 q[4], const CoordW& c, bool edge) {
    float4 r00 = rowlerp(q[0], edge, c.tx);
    float4 r01 = rowlerp(q[1], edge, c.tx);
    float4 r10 = rowlerp(q[2], edge, c.tx);
    float4 r11 = rowlerp(q[3], edge, c.tx);
    float4 e0 = lerp4(r00, r01, c.ty);
    float4 e1 = lerp4(r10, r11, c.ty);
    return lerp4(e0, e1, c.tz);
}

__device__ __forceinline__ float4 reduce8(const float4* q, const CoordW& c) {
    float4 c00 = lerp4(q[0], q[1], c.tx);
    float4 c01 = lerp4(q[2], q[3], c.tx);
    float4 c10 = lerp4(q[4], q[5], c.tx);
    float4 c11 = lerp4(q[6], q[7], c.tx);
    float4 c0 = lerp4(c00, c01, c.ty);
    float4 c1 = lerp4(c10, c11, c.ty);
    return lerp4(c0, c1, c.tz);
}

// ---------------- convert [C,DHW] fp32 -> [DHW,C] bf16 ----------------

template<int VOX>
__device__ __forceinline__ void conv_pair(const float* __restrict__ v,
                                          uint4* __restrict__ w, int i) {
    const float2* __restrict__ c0 = (const float2*)(v);
    const float2* __restrict__ c1 = (const float2*)(v + VOX);
    const float2* __restrict__ c2 = (const float2*)(v + 2 * VOX);
    const float2* __restrict__ c3 = (const float2*)(v + 3 * VOX);
    float2 a = c0[i], b = c1[i], c = c2[i], d = c3[i];
    uint4 u;
    u.x = bfpack(a.x, b.x);
    u.y = bfpack(c.x, d.x);
    u.z = bfpack(a.y, b.y);
    u.w = bfpack(c.y, d.y);
    nt_store4u(u, &w[i]);
}

__global__ __launch_bounds__(256) void conv_all_kernel(
    const float* __restrict__ v0, const float* __restrict__ v1,
    const float* __restrict__ v2, const float* __restrict__ v3,
    uint4* __restrict__ w0, uint4* __restrict__ w1,
    uint4* __restrict__ w2, uint4* __restrict__ w3)
{
    constexpr int P3 = VOX3 / 512, P2 = VOX2 / 512, P1 = VOX1 / 512;
    int b = blockIdx.x, t = threadIdx.x;
    if (b < P3)                 conv_pair<VOX3>(v3, w3, b * 256 + t);
    else if (b < P3 + P2)       conv_pair<VOX2>(v2, w2, (b - P3) * 256 + t);
    else if (b < P3 + P2 + P1)  conv_pair<VOX1>(v1, w1, (b - P3 - P2) * 256 + t);
    else                        conv_pair<VOX0>(v0, w0, (b - P3 - P2 - P1) * 256 + t);
}

__global__ __launch_bounds__(256) void conv_small_kernel(
    const float* __restrict__ v0, const float* __restrict__ v1, const float* __restrict__ v2,
    uint4* __restrict__ w0, uint4* __restrict__ w1, uint4* __restrict__ w2)
{
    constexpr int P2 = VOX2 / 512, P1 = VOX1 / 512;
    int b = blockIdx.x, t = threadIdx.x;
    if (b < P2)            conv_pair<VOX2>(v2, w2, b * 256 + t);
    else if (b < P2 + P1)  conv_pair<VOX1>(v1, w1, (b - P2) * 256 + t);
    else                   conv_pair<VOX0>(v0, w0, (b - P2 - P1) * 256 + t);
}

// ---------------- counting sort ----------------

__device__ __forceinline__ int bin_of(float gx, float gy, float gz) {
    float ux = fminf(fmaxf((gx + 1.0f) * 0.5f, 0.0f), 1.0f);
    float uy = fminf(fmaxf((gy + 1.0f) * 0.5f, 0.0f), 1.0f);
    float uz = fminf(fmaxf((gz + 1.0f) * 0.5f, 0.0f), 1.0f);
    int bx = min((int)(ux * (float)NB), NB - 1);
    int by = min((int)(uy * (float)NB), NB - 1);
    int bz = min((int)(uz * (float)NB), NB - 1);
    return (bz * NB + by) * NB + bx;
}

__global__ __launch_bounds__(256) void bin_hist_kernel(const float* __restrict__ grid,
                                                       unsigned* __restrict__ hist) {
    int p = blockIdx.x * blockDim.x + threadIdx.x;
    float gx = grid[3 * p + 0];
    float gy = grid[3 * p + 1];
    float gz = grid[3 * p + 2];
    atomicAdd(&hist[bin_of(gx, gy, gz)], 1u);
}

__global__ __launch_bounds__(1024) void scan_kernel(const unsigned* __restrict__ hist,
                                                    unsigned* __restrict__ offsets) {
    __shared__ unsigned partial[1024];
    const int t = threadIdx.x;
    const int base = t * 32;
    unsigned sum = 0;
#pragma unroll
    for (int i = 0; i < 32; ++i) sum += hist[base + i];
    partial[t] = sum;
    __syncthreads();
    for (int off = 1; off < 1024; off <<= 1) {
        unsigned v = (t >= off) ? partial[t - off] : 0u;
        __syncthreads();
        partial[t] += v;
        __syncthreads();
    }
    unsigned run = partial[t] - sum;
#pragma unroll
    for (int i = 0; i < 32; ++i) {
        offsets[base + i] = run;
        run += hist[base + i];
    }
}

__global__ __launch_bounds__(256) void scatter_kernel(const float* __restrict__ grid,
                                                      unsigned* __restrict__ offsets,
                                                      float4* __restrict__ sorted) {
    int p = blockIdx.x * blockDim.x + threadIdx.x;
    float gx = grid[3 * p + 0];
    float gy = grid[3 * p + 1];
    float gz = grid[3 * p + 2];
    int b = bin_of(gx, gy, gz);
    unsigned pos = atomicAdd(&offsets[b], 1u);
    sorted[pos] = make_float4(gx, gy, gz, __int_as_float(p));
}

// ---------------- gather (Tier A: all volumes bf16-interleaved) ----------------

template<int D>
__device__ __forceinline__ void fetch_rows(const char* __restrict__ w, const CoordW& c,
                                           int xm, uint4 q[4]) {
    q[0] = load16(w + 8 * (c.b00 + xm));
    q[1] = load16(w + 8 * (c.b01 + xm));
    q[2] = load16(w + 8 * (c.b10 + xm));
    q[3] = load16(w + 8 * (c.b11 + xm));
}

__global__ __launch_bounds__(256) void gather_a_kernel(
    const float4* __restrict__ sorted,
    const char* __restrict__ w0, const char* __restrict__ w1,
    const char* __restrict__ w2, const char* __restrict__ w3,
    uint4* __restrict__ wsout)   // [NPTS][2] uint4 = [NPTS][16] bf16, original order
{
    int bid = blockIdx.x;
    int sb = (bid & 7) * (int)(gridDim.x >> 3) + (bid >> 3);
    int s = sb * 256 + (int)threadIdx.x;
    float4 gp = sorted[s];
    float gx = gp.x, gy = gp.y, gz = gp.z;
    int p = __float_as_int(gp.w);

    CoordW c0 = mkcoord<32>(gx, gy, gz);
    CoordW c1 = mkcoord<64>(gx, gy, gz);
    CoordW c2 = mkcoord<128>(gx, gy, gz);
    CoordW c3 = mkcoord<256>(gx, gy, gz);
    int xm0 = min(c0.x0, 30);  bool e0 = (c0.x0 == 31);
    int xm1 = min(c1.x0, 62);  bool e1 = (c1.x0 == 63);
    int xm2 = min(c2.x0, 126); bool e2 = (c2.x0 == 127);
    int xm3 = min(c3.x0, 254); bool e3 = (c3.x0 == 255);

    uint4 qa[4], qb[4], qc[4], qd[4];
    fetch_rows<32>(w0, c0, xm0, qa);
    fetch_rows<64>(w1, c1, xm1, qb);
    fetch_rows<128>(w2, c2, xm2, qc);
    fetch_rows<256>(w3, c3, xm3, qd);

    float4 f0 = reduce_bf(qa, c0, e0);
    float4 f1 = reduce_bf(qb, c1, e1);
    float4 f2 = reduce_bf(qc, c2, e2);
    float4 f3 = reduce_bf(qd, c3, e3);

    uint4 ua, ub;
    ua.x = bfpack(f0.x, f0.y); ua.y = bfpack(f0.z, f0.w);
    ua.z = bfpack(f1.x, f1.y); ua.w = bfpack(f1.z, f1.w);
    ub.x = bfpack(f2.x, f2.y); ub.y = bfpack(f2.z, f2.w);
    ub.z = bfpack(f3.x, f3.y); ub.w = bfpack(f3.z, f3.w);

    uint4* w = wsout + (size_t)p * 2;
    nt_store4u(ua, w + 0);
    nt_store4u(ub, w + 1);
}

// ---------------- gather (Tier B: small vols bf16, vol3 fp32 native) ----------------

__global__ __launch_bounds__(256) void gather_b_kernel(
    const float4* __restrict__ sorted,
    const char* __restrict__ w0, const char* __restrict__ w1,
    const char* __restrict__ w2, const float* __restrict__ v3,
    uint4* __restrict__ wsout)
{
    int bid = blockIdx.x;
    int sb = (bid & 7) * (int)(gridDim.x >> 3) + (bid >> 3);
    int s = sb * 256 + (int)threadIdx.x;
    float4 gp = sorted[s];
    float gx = gp.x, gy = gp.y, gz = gp.z;
    int p = __float_as_int(gp.w);

    CoordW c0 = mkcoord<32>(gx, gy, gz);
    CoordW c1 = mkcoord<64>(gx, gy, gz);
    CoordW c2 = mkcoord<128>(gx, gy, gz);
    CoordW c3 = mkcoord<256>(gx, gy, gz);
    int xm0 = min(c0.x0, 30);  bool e0 = (c0.x0 == 31);
    int xm1 = min(c1.x0, 62);  bool e1 = (c1.x0 == 63);
    int xm2 = min(c2.x0, 126); bool e2 = (c2.x0 == 127);
    int xm3 = min(c3.x0, 254); bool e3 = (c3.x0 == 255);

    uint4 qa[4], qb[4], qc[4];
    fetch_rows<32>(w0, c0, xm0, qa);
    fetch_rows<64>(w1, c1, xm1, qb);
    fetch_rows<128>(w2, c2, xm2, qc);

    float2 qd[16];
#pragma unroll
    for (int ch = 0; ch < 4; ++ch) {
        const float* __restrict__ vc = v3 + (size_t)ch * VOX3;
        qd[ch * 4 + 0] = *(const float2*)(vc + c3.b00 + xm3);
        qd[ch * 4 + 1] = *(const float2*)(vc + c3.b01 + xm3);
        qd[ch * 4 + 2] = *(const float2*)(vc + c3.b10 + xm3);
        qd[ch * 4 + 3] = *(const float2*)(vc + c3.b11 + xm3);
    }

    float4 f0 = reduce_bf(qa, c0, e0);
    float4 f1 = reduce_bf(qb, c1, e1);
    float4 f2 = reduce_bf(qc, c2, e2);

    float r3[4];
#pragma unroll
    for (int ch = 0; ch < 4; ++ch) {
        float v00a = e3 ? qd[ch * 4 + 0].y : qd[ch * 4 + 0].x, v00b = qd[ch * 4 + 0].y;
        float v01a = e3 ? qd[ch * 4 + 1].y : qd[ch * 4 + 1].x, v01b = qd[ch * 4 + 1].y;
        float v10a = e3 ? qd[ch * 4 + 2].y : qd[ch * 4 + 2].x, v10b = qd[ch * 4 + 2].y;
        float v11a = e3 ? qd[ch * 4 + 3].y : qd[ch * 4 + 3].x, v11b = qd[ch * 4 + 3].y;
        float c00 = v00a + (v00b - v00a) * c3.tx;
        float c01 = v01a + (v01b - v01a) * c3.tx;
        float c10 = v10a + (v10b - v10a) * c3.tx;
        float c11 = v11a + (v11b - v11a) * c3.tx;
        float ee0 = c00 + (c01 - c00) * c3.ty;
        float ee1 = c10 + (c11 - c10) * c3.ty;
        r3[ch] = ee0 + (ee1 - ee0) * c3.tz;
    }

    uint4 ua, ub;
    ua.x = bfpack(f0.x, f0.y); ua.y = bfpack(f0.z, f0.w);
    ua.z = bfpack(f1.x, f1.y); ua.w = bfpack(f1.z, f1.w);
    ub.x = bfpack(f2.x, f2.y); ub.y = bfpack(f2.z, f2.w);
    ub.z = bfpack(r3[0], r3[1]); ub.w = bfpack(r3[2], r3[3]);

    uint4* w = wsout + (size_t)p * 2;
    nt_store4u(ua, w + 0);
    nt_store4u(ub, w + 1);
}

// ---------------- final: [P][16] bf16 (original order) -> [16][P] fp32 ----------------

__global__ __launch_bounds__(256) void final_kernel(const uint4* __restrict__ wsout,
                                                    float* __restrict__ out) {
    int p = blockIdx.x * blockDim.x + threadIdx.x;
    uint4 a = wsout[2 * p], b = wsout[2 * p + 1];
    __builtin_nontemporal_store(bflo(a.x), &out[ 0 * NPTS + p]);
    __builtin_nontemporal_store(bfhi(a.x), &out[ 1 * NPTS + p]);
    __builtin_nontemporal_store(bflo(a.y), &out[ 2 * NPTS + p]);
    __builtin_nontemporal_store(bfhi(a.y), &out[ 3 * NPTS + p]);
    __builtin_nontemporal_store(bflo(a.z), &out[ 4 * NPTS + p]);
    __builtin_nontemporal_store(bfhi(a.z), &out[ 5 * NPTS + p]);
    __builtin_nontemporal_store(bflo(a.w), &out[ 6 * NPTS + p]);
    __builtin_nontemporal_store(bfhi(a.w), &out[ 7 * NPTS + p]);
    __builtin_nontemporal_store(bflo(b.x), &out[ 8 * NPTS + p]);
    __builtin_nontemporal_store(bfhi(b.x), &out[ 9 * NPTS + p]);
    __builtin_nontemporal_store(bflo(b.y), &out[10 * NPTS + p]);
    __builtin_nontemporal_store(bfhi(b.y), &out[11 * NPTS + p]);
    __builtin_nontemporal_store(bflo(b.z), &out[12 * NPTS + p]);
    __builtin_nontemporal_store(bfhi(b.z), &out[13 * NPTS + p]);
    __builtin_nontemporal_store(bflo(b.w), &out[14 * NPTS + p]);
    __builtin_nontemporal_store(bfhi(b.w), &out[15 * NPTS + p]);
}

// ---------------- fallback paths (fp32, from round 2/4) ----------------

template<int D>
__device__ __forceinline__ float4 sample_inter(const float4* __restrict__ v,
                                               float gx, float gy, float gz) {
    CoordW c = mkcoord<D>(gx, gy, gz);
    float4 q[8];
    q[0] = v[c.b00 + c.x0]; q[1] = v[c.b00 + c.x1];
    q[2] = v[c.b01 + c.x0]; q[3] = v[c.b01 + c.x1];
    q[4] = v[c.b10 + c.x0]; q[5] = v[c.b10 + c.x1];
    q[6] = v[c.b11 + c.x0]; q[7] = v[c.b11 + c.x1];
    return reduce8(q, c);
}

template<int D>
__device__ __forceinline__ float4 sample_direct(const float* __restrict__ v,
                                                float gx, float gy, float gz) {
    CoordW c = mkcoord<D>(gx, gy, gz);
    float r[4];
#pragma unroll
    for (int ch = 0; ch < 4; ++ch) {
        const float* __restrict__ vc = v + (size_t)ch * (D * D * D);
        float c000 = vc[c.b00 + c.x0], c001 = vc[c.b00 + c.x1];
        float c010 = vc[c.b01 + c.x0], c011 = vc[c.b01 + c.x1];
        float c100 = vc[c.b10 + c.x0], c101 = vc[c.b10 + c.x1];
        float c110 = vc[c.b11 + c.x0], c111 = vc[c.b11 + c.x1];
        float c00 = c000 + (c001 - c000) * c.tx;
        float c01 = c010 + (c011 - c010) * c.tx;
        float c10 = c100 + (c101 - c100) * c.tx;
        float c11 = c110 + (c111 - c110) * c.tx;
        float e0 = c00 + (c01 - c00) * c.ty;
        float e1 = c10 + (c11 - c10) * c.ty;
        r[ch] = e0 + (e1 - e0) * c.tz;
    }
    return make_float4(r[0], r[1], r[2], r[3]);
}

__global__ __launch_bounds__(256) void xpose_all_kernel(
    const float* __restrict__ v0, const float* __restrict__ v1, const float* __restrict__ v2,
    float4* __restrict__ w0, float4* __restrict__ w1, float4* __restrict__ w2)
{
    constexpr int B2 = VOX2 / 256, B1 = VOX1 / 256;
    int b = blockIdx.x;
    int t = threadIdx.x;
    if (b < B2) {
        int v = b * 256 + t;
        w2[v] = make_float4(v2[v], v2[v + VOX2], v2[v + 2 * VOX2], v2[v + 3 * VOX2]);
    } else if (b < B2 + B1) {
        int v = (b - B2) * 256 + t;
        w1[v] = make_float4(v1[v], v1[v + VOX1], v1[v + 2 * VOX1], v1[v + 3 * VOX1]);
    } else {
        int v = (b - B2 - B1) * 256 + t;
        w0[v] = make_float4(v0[v], v0[v + VOX0], v0[v + 2 * VOX0], v0[v + 3 * VOX0]);
    }
}

__global__ __launch_bounds__(256) void mg_inter_kernel(
    const float* __restrict__ grid,
    const float4* __restrict__ w0, const float4* __restrict__ w1,
    const float4* __restrict__ w2, const float* __restrict__ v3,
    float* __restrict__ out)
{
    int p = blockIdx.x * blockDim.x + threadIdx.x;
    float gx = grid[3 * p + 0];
    float gy = grid[3 * p + 1];
    float gz = grid[3 * p + 2];
    float4 f0 = sample_inter<32>(w0, gx, gy, gz);
    float4 f1 = sample_inter<64>(w1, gx, gy, gz);
    float4 f2 = sample_inter<128>(w2, gx, gy, gz);
    float4 f3 = sample_direct<256>(v3, gx, gy, gz);
    out[ 0 * NPTS + p] = f0.x; out[ 1 * NPTS + p] = f0.y;
    out[ 2 * NPTS + p] = f0.z; out[ 3 * NPTS + p] = f0.w;
    out[ 4 * NPTS + p] = f1.x; out[ 5 * NPTS + p] = f1.y;
    out[ 6 * NPTS + p] = f1.z; out[ 7 * NPTS + p] = f1.w;
    out[ 8 * NPTS + p] = f2.x; out[ 9 * NPTS + p] = f2.y;
    out[10 * NPTS + p] = f2.z; out[11 * NPTS + p] = f2.w;
    out[12 * NPTS + p] = f3.x; out[13 * NPTS + p] = f3.y;
    out[14 * NPTS + p] = f3.z; out[15 * NPTS + p] = f3.w;
}

__global__ __launch_bounds__(256) void mg_direct_kernel(
    const float* __restrict__ grid,
    const float* __restrict__ v0, const float* __restrict__ v1,
    const float* __restrict__ v2, const float* __restrict__ v3,
    float* __restrict__ out)
{
    int p = blockIdx.x * blockDim.x + threadIdx.x;
    float gx = grid[3 * p + 0];
    float gy = grid[3 * p + 1];
    float gz = grid[3 * p + 2];
    float4 f0 = sample_direct<32>(v0, gx, gy, gz);
    float4 f1 = sample_direct<64>(v1, gx, gy, gz);
    float4 f2 = sample_direct<128>(v2, gx, gy, gz);
    float4 f3 = sample_direct<256>(v3, gx, gy, gz);
    out[ 0 * NPTS + p] = f0.x; out[ 1 * NPTS + p] = f0.y;
    out[ 2 * NPTS + p] = f0.z; out[ 3 * NPTS + p] = f0.w;
    out[ 4 * NPTS + p] = f1.x; out[ 5 * NPTS + p] = f1.y;
    out[ 6 * NPTS + p] = f1.z; out[ 7 * NPTS + p] = f1.w;
    out[ 8 * NPTS + p] = f2.x; out[ 9 * NPTS + p] = f2.y;
    out[10 * NPTS + p] = f2.z; out[11 * NPTS + p] = f2.w;
    out[12 * NPTS + p] = f3.x; out[13 * NPTS + p] = f3.y;
    out[14 * NPTS + p] = f3.z; out[15 * NPTS + p] = f3.w;
}

// ---------------- launch ----------------

extern "C" void kernel_launch(void* const* d_in, const int* in_sizes, int n_in,
                              void* d_out, int out_size, void* d_ws, size_t ws_size,
                              hipStream_t stream) {
    const float* grid = (const float*)d_in[0];
    const float* v0   = (const float*)d_in[1];   // [4,32,32,32]
    const float* v1   = (const float*)d_in[2];   // [4,64,64,64]
    const float* v2   = (const float*)d_in[3];   // [4,128,128,128]
    const float* v3   = (const float*)d_in[4];   // [4,256,256,256]
    float* out = (float*)d_out;

    constexpr size_t SZ_W3   = (size_t)VOX3 * 8;     // 128 MB bf16 interleaved
    constexpr size_t SZ_W2   = (size_t)VOX2 * 8;     // 16 MB
    constexpr size_t SZ_W1   = (size_t)VOX1 * 8;     // 2 MB
    constexpr size_t SZ_W0   = (size_t)VOX0 * 8;     // 256 KB
    constexpr size_t SZ_SORT = (size_t)NPTS * 16;    // 16 MB
    constexpr size_t SZ_WSO  = (size_t)NPTS * 32;    // 32 MB
    constexpr size_t SZ_H    = (size_t)NBINS * 4;    // 128 KB

    constexpr size_t WS_A = SZ_W3 + SZ_W2 + SZ_W1 + SZ_W0 + SZ_SORT + SZ_WSO + 2 * SZ_H; // ~194.5 MB
    constexpr size_t WS_B = WS_A - SZ_W3;                                                // ~66.5 MB
    constexpr size_t WS_INTER = (size_t)(VOX0 + VOX1 + VOX2) * 16;                       // 36.5 MB

    const int threads = 256;
    const int pt_blocks = NPTS / threads;   // 4096
    char* ws = (char*)d_ws;

    if (ws_size >= WS_A) {
        char*     w3     = ws;
        char*     w2     = w3 + SZ_W3;
        char*     w1     = w2 + SZ_W2;
        char*     w0     = w1 + SZ_W1;
        float4*   sorted = (float4*)(w0 + SZ_W0);
        uint4*    wsout  = (uint4*)((char*)sorted + SZ_SORT);
        unsigned* hist   = (unsigned*)((char*)wsout + SZ_WSO);
        unsigned* offs   = (unsigned*)((char*)hist + SZ_H);

        (void)hipMemsetAsync(hist, 0, SZ_H, stream);
        conv_all_kernel<<<(VOX0 + VOX1 + VOX2 + VOX3) / 512, threads, 0, stream>>>(
            v0, v1, v2, v3, (uint4*)w0, (uint4*)w1, (uint4*)w2, (uint4*)w3);
        bin_hist_kernel<<<pt_blocks, threads, 0, stream>>>(grid, hist);
        scan_kernel<<<1, 1024, 0, stream>>>(hist, offs);
        scatter_kernel<<<pt_blocks, threads, 0, stream>>>(grid, offs, sorted);
        gather_a_kernel<<<pt_blocks, threads, 0, stream>>>(sorted, w0, w1, w2, w3, wsout);
        final_kernel<<<pt_blocks, threads, 0, stream>>>(wsout, out);
    } else if (ws_size >= WS_B) {
        char*     w2     = ws;
        char*     w1     = w2 + SZ_W2;
        char*     w0     = w1 + SZ_W1;
        float4*   sorted = (float4*)(w0 + SZ_W0);
        uint4*    wsout  = (uint4*)((char*)sorted + SZ_SORT);
        unsigned* hist   = (unsigned*)((char*)wsout + SZ_WSO);
        unsigned* offs   = (unsigned*)((char*)hist + SZ_H);

        (void)hipMemsetAsync(hist, 0, SZ_H, stream);
        conv_small_kernel<<<(VOX0 + VOX1 + VOX2) / 512, threads, 0, stream>>>(
            v0, v1, v2, (uint4*)w0, (uint4*)w1, (uint4*)w2);
        bin_hist_kernel<<<pt_blocks, threads, 0, stream>>>(grid, hist);
        scan_kernel<<<1, 1024, 0, stream>>>(hist, offs);
        scatter_kernel<<<pt_blocks, threads, 0, stream>>>(grid, offs, sorted);
        gather_b_kernel<<<pt_blocks, threads, 0, stream>>>(sorted, w0, w1, w2, v3, wsout);
        final_kernel<<<pt_blocks, threads, 0, stream>>>(wsout, out);
    } else if (ws_size >= WS_INTER) {
        float4* w0 = (float4*)d_ws;
        float4* w1 = w0 + VOX0;
        float4* w2 = w1 + VOX1;
        xpose_all_kernel<<<(VOX0 + VOX1 + VOX2) / threads, threads, 0, stream>>>(
            v0, v1, v2, w0, w1, w2);
        mg_inter_kernel<<<pt_blocks, threads, 0, stream>>>(grid, w0, w1, w2, v3, out);
    } else {
        mg_direct_kernel<<<pt_blocks, threads, 0, stream>>>(grid, v0, v1, v2, v3, out);
    }
}